// Round 1
// baseline (1418.063 us; speedup 1.0000x reference)
//
#include <hip/hip_runtime.h>
#include <stdint.h>

#define N_NODES 50000
#define N_EDGES 800000
#define HID 128

typedef __attribute__((ext_vector_type(8))) short bf16x8;
typedef __attribute__((ext_vector_type(4))) float f32x4;

// round-half-up fp32 -> bf16 pair, packed into one u32 (x = low half)
__device__ inline uint32_t pack_bf16(float x, float y) {
    uint32_t a = __builtin_bit_cast(uint32_t, x) + 0x8000u;
    uint32_t b = __builtin_bit_cast(uint32_t, y) + 0x8000u;
    return (b & 0xffff0000u) | (a >> 16);
}

__device__ inline unsigned short cvt_bf16(float x) {
    return (unsigned short)((__builtin_bit_cast(uint32_t, x) + 0x8000u) >> 16);
}

// 8 consecutive fp32 (32B aligned) -> bf16x8 fragment
__device__ inline bf16x8 load_row8_bf16(const float* p) {
    const float4* q = (const float4*)p;
    float4 u = q[0], v = q[1];
    union { bf16x8 v8; uint32_t u32[4]; } r;
    r.u32[0] = pack_bf16(u.x, u.y);
    r.u32[1] = pack_bf16(u.z, u.w);
    r.u32[2] = pack_bf16(v.x, v.y);
    r.u32[3] = pack_bf16(v.z, v.w);
    return r.v8;
}

// --- prep: shuffle We (384x128) and Wn (256x128) fp32 -> bf16 in MFMA
// B-fragment order: frag index (kk, t), lane l holds B[kk*32 + (l>>4)*8 + j][t*16 + (l&15)]
// stored at ((kk*8 + t)*64 + l)*8 + j.
#define WE_SHUF_ELEMS (12 * 8 * 64 * 8)  // 49152
#define WN_SHUF_ELEMS (8 * 8 * 64 * 8)   // 32768
__global__ void prep_kernel(const float* __restrict__ We, const float* __restrict__ Wn,
                            unsigned short* __restrict__ We_shuf,
                            unsigned short* __restrict__ Wn_shuf) {
    int tid = blockIdx.x * blockDim.x + threadIdx.x;
    if (tid < WE_SHUF_ELEMS) {
        int j = tid & 7, lane = (tid >> 3) & 63, tt = tid >> 9;
        int t = tt & 7, kk = tt >> 3;            // kk in [0,12)
        int k = kk * 32 + (lane >> 4) * 8 + j;
        int n = t * 16 + (lane & 15);
        We_shuf[tid] = cvt_bf16(We[k * HID + n]);
    } else if (tid < WE_SHUF_ELEMS + WN_SHUF_ELEMS) {
        int id = tid - WE_SHUF_ELEMS;
        int j = id & 7, lane = (id >> 3) & 63, tt = id >> 9;
        int t = tt & 7, kk = tt >> 3;            // kk in [0,8)
        int k = kk * 32 + (lane >> 4) * 8 + j;
        int n = t * 16 + (lane & 15);
        Wn_shuf[id] = cvt_bf16(Wn[k * HID + n]);
    }
}

// --- counting sort of edges by dst ---
// bend[] usage: memset 0 -> histogram -> exclusive-scan (start offsets) ->
// scatter (atomicAdd turns it into END offsets). gather: start = bend[n-1], end = bend[n].
__global__ void hist_kernel(const int* __restrict__ dst, int* __restrict__ bend) {
    int e = blockIdx.x * blockDim.x + threadIdx.x;
    if (e < N_EDGES) atomicAdd(&bend[dst[e]], 1);
}

#define SCAN_T 1024
__global__ __launch_bounds__(1024) void scan_kernel(int* __restrict__ bend) {
    __shared__ int part[SCAN_T];
    int t = threadIdx.x;
    const int chunk = (N_NODES + SCAN_T - 1) / SCAN_T;  // 49
    int lo = t * chunk;
    int hi = lo + chunk;
    if (hi > N_NODES) hi = N_NODES;
    if (lo > N_NODES) lo = N_NODES;
    int s = 0;
    for (int i = lo; i < hi; ++i) s += bend[i];
    part[t] = s;
    __syncthreads();
    // Hillis-Steele inclusive scan over the 1024 partials
    for (int off = 1; off < SCAN_T; off <<= 1) {
        int v = 0;
        if (t >= off) v = part[t - off];
        __syncthreads();
        if (t >= off) part[t] += v;
        __syncthreads();
    }
    int excl = (t == 0) ? 0 : part[t - 1];
    // in-place rewrite: B[i] = exclusive prefix (each thread owns its chunk)
    for (int i = lo; i < hi; ++i) {
        int v = bend[i];
        bend[i] = excl;
        excl += v;
    }
}

__global__ void scatter_kernel(const int* __restrict__ dst, int* __restrict__ bend,
                               int* __restrict__ order) {
    int e = blockIdx.x * blockDim.x + threadIdx.x;
    if (e < N_EDGES) {
        int pos = atomicAdd(&bend[dst[e]], 1);
        order[pos] = e;
    }
}

// --- edge kernel: per wave, 32 edges x 128 cols. NO atomics.
// out1[e] = relu(concat(nfeats[src], efeats[e], nfeats[dst]) @ We + be) + efeats[e]
__global__ __launch_bounds__(256) void edge_kernel(
    const float* __restrict__ nfeats, const float* __restrict__ efeats,
    const int* __restrict__ src, const int* __restrict__ dst,
    const unsigned short* __restrict__ We_shuf, const float* __restrict__ be,
    float* __restrict__ out1) {
    int wid = blockIdx.x * 4 + (threadIdx.x >> 6);
    int lane = threadIdx.x & 63;
    int e0 = wid * 32;
    int m = lane & 15, quad = lane >> 4;

    int r0 = e0 + m, r1 = e0 + 16 + m;
    const float* pa0[3], *pa1[3];
    pa0[0] = nfeats + (size_t)src[r0] * HID;
    pa0[1] = efeats + (size_t)r0 * HID;
    pa0[2] = nfeats + (size_t)dst[r0] * HID;
    pa1[0] = nfeats + (size_t)src[r1] * HID;
    pa1[1] = efeats + (size_t)r1 * HID;
    pa1[2] = nfeats + (size_t)dst[r1] * HID;

    f32x4 acc[2][8];
#pragma unroll
    for (int mi = 0; mi < 2; ++mi)
#pragma unroll
        for (int t = 0; t < 8; ++t) acc[mi][t] = (f32x4){0.f, 0.f, 0.f, 0.f};

    const bf16x8* W = (const bf16x8*)We_shuf;

#pragma unroll
    for (int kk = 0; kk < 12; ++kk) {
        int k = kk * 32 + quad * 8;       // wave-uniform segment: k/128 same for all lanes
        int seg = k >> 7, off = k & 127;
        bf16x8 a0 = load_row8_bf16(pa0[seg] + off);
        bf16x8 a1 = load_row8_bf16(pa1[seg] + off);
#pragma unroll
        for (int t = 0; t < 8; ++t) {
            bf16x8 b = W[(kk * 8 + t) * 64 + lane];
            acc[0][t] = __builtin_amdgcn_mfma_f32_16x16x32_bf16(a0, b, acc[0][t], 0, 0, 0);
            acc[1][t] = __builtin_amdgcn_mfma_f32_16x16x32_bf16(a1, b, acc[1][t], 0, 0, 0);
        }
    }

    // bias per column (col n = t*16 + (lane&15))
    float bev[8];
#pragma unroll
    for (int t = 0; t < 8; ++t) bev[t] = be[t * 16 + m];

    // epilogue: C/D layout col = lane&15, row = quad*4 + reg
#pragma unroll
    for (int mi = 0; mi < 2; ++mi) {
#pragma unroll
        for (int r = 0; r < 4; ++r) {
            int e = e0 + mi * 16 + quad * 4 + r;
            const float* ef = efeats + (size_t)e * HID;
            float* o = out1 + (size_t)e * HID;
#pragma unroll
            for (int t = 0; t < 8; ++t) {
                int n = t * 16 + m;
                float v = acc[mi][t][r] + bev[t];
                o[n] = fmaxf(v, 0.0f) + ef[n];
            }
        }
    }
}

// --- gather kernel: one wave per node. h[n] = mean over edges e with dst==n of
// (out1[e] - efeats[e])  (== m[e] exactly mod 1 ulp of the fp32 add).
__global__ __launch_bounds__(256) void gather_kernel(
    const float* __restrict__ out1, const float* __restrict__ efeats,
    const int* __restrict__ order, const int* __restrict__ bend,
    float* __restrict__ h) {
    int wid = blockIdx.x * 4 + (threadIdx.x >> 6);
    if (wid >= N_NODES) return;
    int lane = threadIdx.x & 63;
    int start = (wid == 0) ? 0 : bend[wid - 1];
    int end = bend[wid];
    float ax = 0.0f, ay = 0.0f;
    int j = start;
    // unroll by 2 for memory-level parallelism (4 x 512B loads in flight)
    for (; j + 2 <= end; j += 2) {
        int ea = order[j], eb = order[j + 1];
        float2 o1 = ((const float2*)(out1 + (size_t)ea * HID))[lane];
        float2 f1 = ((const float2*)(efeats + (size_t)ea * HID))[lane];
        float2 o2 = ((const float2*)(out1 + (size_t)eb * HID))[lane];
        float2 f2 = ((const float2*)(efeats + (size_t)eb * HID))[lane];
        ax += (o1.x - f1.x) + (o2.x - f2.x);
        ay += (o1.y - f1.y) + (o2.y - f2.y);
    }
    if (j < end) {
        int ea = order[j];
        float2 o1 = ((const float2*)(out1 + (size_t)ea * HID))[lane];
        float2 f1 = ((const float2*)(efeats + (size_t)ea * HID))[lane];
        ax += o1.x - f1.x;
        ay += o1.y - f1.y;
    }
    int deg = end - start;
    float inv = (deg > 0) ? 1.0f / (float)deg : 0.0f;
    float2 r;
    r.x = ax * inv;
    r.y = ay * inv;
    ((float2*)(h + (size_t)wid * HID))[lane] = r;
}

// --- node kernel: per wave, 16 nodes x 128 cols.
// out0 = relu(concat(nfeats, h) @ Wn + bn) + nfeats   (h already mean-reduced)
__global__ __launch_bounds__(256) void node_kernel(
    const float* __restrict__ nfeats, const unsigned short* __restrict__ Wn_shuf,
    const float* __restrict__ bn, const float* __restrict__ h,
    float* __restrict__ out0) {
    int wid = blockIdx.x * 4 + (threadIdx.x >> 6);
    int n0 = wid * 16;
    if (n0 >= N_NODES) return;
    int lane = threadIdx.x & 63;
    int m = lane & 15, quad = lane >> 4;
    int row = n0 + m;
    const float* pn = nfeats + (size_t)row * HID;
    const float* ph = h + (size_t)row * HID;

    f32x4 acc[8];
#pragma unroll
    for (int t = 0; t < 8; ++t) acc[t] = (f32x4){0.f, 0.f, 0.f, 0.f};

    const bf16x8* W = (const bf16x8*)Wn_shuf;

#pragma unroll
    for (int kk = 0; kk < 8; ++kk) {
        int k = kk * 32 + quad * 8;   // segment (k<128 vs >=128) wave-uniform per kk
        bf16x8 a = (k < 128) ? load_row8_bf16(pn + k)
                             : load_row8_bf16(ph + (k - 128));
#pragma unroll
        for (int t = 0; t < 8; ++t) {
            bf16x8 b = W[(kk * 8 + t) * 64 + lane];
            acc[t] = __builtin_amdgcn_mfma_f32_16x16x32_bf16(a, b, acc[t], 0, 0, 0);
        }
    }

    float bnv[8];
#pragma unroll
    for (int t = 0; t < 8; ++t) bnv[t] = bn[t * 16 + m];

#pragma unroll
    for (int r = 0; r < 4; ++r) {
        int rw = n0 + quad * 4 + r;
        const float* nf = nfeats + (size_t)rw * HID;
        float* o = out0 + (size_t)rw * HID;
#pragma unroll
        for (int t = 0; t < 8; ++t) {
            int n = t * 16 + m;
            float v = fmaxf(acc[t][r] + bnv[t], 0.0f);
            o[n] = v + nf[n];
        }
    }
}

extern "C" void kernel_launch(void* const* d_in, const int* in_sizes, int n_in,
                              void* d_out, int out_size, void* d_ws, size_t ws_size,
                              hipStream_t stream) {
    const float* nfeats = (const float*)d_in[0];
    const float* efeats = (const float*)d_in[1];
    const int* src = (const int*)d_in[2];
    const int* dst = (const int*)d_in[3];
    const float* We = (const float*)d_in[4];
    const float* be = (const float*)d_in[5];
    const float* Wn = (const float*)d_in[6];
    const float* bn = (const float*)d_in[7];

    float* out0 = (float*)d_out;                       // [N_NODES, HID]
    float* out1 = out0 + (size_t)N_NODES * HID;        // [N_EDGES, HID]

    // Counting-sort scratch lives in the out0 region of d_out (dead until
    // node_kernel overwrites out0 at the very end): order[800000] + bend[50000]
    // = 3.4 MB << 25.6 MB.
    int* order = (int*)d_out;
    int* bend = order + N_EDGES;

    // workspace: h (N*H fp32 mean-reduced messages) | We_shuf (bf16) | Wn_shuf (bf16)
    float* h = (float*)d_ws;
    unsigned short* We_shuf = (unsigned short*)(h + (size_t)N_NODES * HID);  // byte 25,600,000 (16B aligned)
    unsigned short* Wn_shuf = We_shuf + WE_SHUF_ELEMS;

    // zero the histogram (out/ws poisoned before every launch)
    hipMemsetAsync(bend, 0, N_NODES * sizeof(int), stream);

    prep_kernel<<<(WE_SHUF_ELEMS + WN_SHUF_ELEMS) / 256, 256, 0, stream>>>(We, Wn, We_shuf, Wn_shuf);

    hist_kernel<<<N_EDGES / 256, 256, 0, stream>>>(dst, bend);
    scan_kernel<<<1, SCAN_T, 0, stream>>>(bend);
    scatter_kernel<<<N_EDGES / 256, 256, 0, stream>>>(dst, bend, order);

    // 800000 edges / 32 per wave = 25000 waves / 4 per block = 6250 blocks
    edge_kernel<<<6250, 256, 0, stream>>>(nfeats, efeats, src, dst, We_shuf, be, out1);

    // 50000 nodes / 1 wave each / 4 per block = 12500 blocks
    gather_kernel<<<12500, 256, 0, stream>>>(out1, efeats, order, bend, h);

    // 50000 nodes / 16 per wave = 3125 waves -> 782 blocks (guarded)
    node_kernel<<<782, 256, 0, stream>>>(nfeats, Wn_shuf, bn, h, out0);
}

// Round 2
// 1247.927 us; speedup vs baseline: 1.1363x; 1.1363x over previous
//
#include <hip/hip_runtime.h>
#include <stdint.h>

#define N_NODES 50000
#define N_EDGES 800000
#define HID 128

typedef __attribute__((ext_vector_type(8))) short bf16x8;
typedef __attribute__((ext_vector_type(4))) float f32x4;

// round-half-up fp32 -> bf16 pair, packed into one u32 (x = low half)
__device__ inline uint32_t pack_bf16(float x, float y) {
    uint32_t a = __builtin_bit_cast(uint32_t, x) + 0x8000u;
    uint32_t b = __builtin_bit_cast(uint32_t, y) + 0x8000u;
    return (b & 0xffff0000u) | (a >> 16);
}

__device__ inline unsigned short cvt_bf16(float x) {
    return (unsigned short)((__builtin_bit_cast(uint32_t, x) + 0x8000u) >> 16);
}

// 8 consecutive fp32 (32B aligned) -> bf16x8 fragment
__device__ inline bf16x8 load_row8_bf16(const float* p) {
    const float4* q = (const float4*)p;
    float4 u = q[0], v = q[1];
    union { bf16x8 v8; uint32_t u32[4]; } r;
    r.u32[0] = pack_bf16(u.x, u.y);
    r.u32[1] = pack_bf16(u.z, u.w);
    r.u32[2] = pack_bf16(v.x, v.y);
    r.u32[3] = pack_bf16(v.z, v.w);
    return r.v8;
}

// async 16B global->LDS (lane l writes lds_base + l*16; source per-lane)
__device__ inline void gload16(const float* g, float* l) {
    __builtin_amdgcn_global_load_lds(
        (const __attribute__((address_space(1))) void*)g,
        (__attribute__((address_space(3))) void*)l, 16, 0, 0);
}

// LDS efeats tile: logical (row, c16-chunk) stored at chunk index c16 ^ (row&7).
// Same swizzle applied at stage-source, fragment read, and epilogue read.
__device__ inline float lds_ef_read(const float* ef, int row, int n) {
    return ef[row * 128 + ((((n >> 2) ^ (row & 7)) << 2) | (n & 3))];
}

__device__ inline bf16x8 load_frag_lds(const float* ef, int row, int c16) {
    int s = row & 7;
    float4 u = *(const float4*)(ef + row * 128 + ((c16 ^ s) << 2));
    float4 v = *(const float4*)(ef + row * 128 + (((c16 + 1) ^ s) << 2));
    union { bf16x8 v8; uint32_t u32[4]; } r;
    r.u32[0] = pack_bf16(u.x, u.y);
    r.u32[1] = pack_bf16(u.z, u.w);
    r.u32[2] = pack_bf16(v.x, v.y);
    r.u32[3] = pack_bf16(v.z, v.w);
    return r.v8;
}

// --- prep: shuffle We (384x128) and Wn (256x128) fp32 -> bf16 in MFMA
// B-fragment order: frag index (kk, t), lane l holds B[kk*32 + (l>>4)*8 + j][t*16 + (l&15)]
#define WE_SHUF_ELEMS (12 * 8 * 64 * 8)  // 49152
#define WN_SHUF_ELEMS (8 * 8 * 64 * 8)   // 32768
__global__ void prep_kernel(const float* __restrict__ We, const float* __restrict__ Wn,
                            unsigned short* __restrict__ We_shuf,
                            unsigned short* __restrict__ Wn_shuf) {
    int tid = blockIdx.x * blockDim.x + threadIdx.x;
    if (tid < WE_SHUF_ELEMS) {
        int j = tid & 7, lane = (tid >> 3) & 63, tt = tid >> 9;
        int t = tt & 7, kk = tt >> 3;
        int k = kk * 32 + (lane >> 4) * 8 + j;
        int n = t * 16 + (lane & 15);
        We_shuf[tid] = cvt_bf16(We[k * HID + n]);
    } else if (tid < WE_SHUF_ELEMS + WN_SHUF_ELEMS) {
        int id = tid - WE_SHUF_ELEMS;
        int j = id & 7, lane = (id >> 3) & 63, tt = id >> 9;
        int t = tt & 7, kk = tt >> 3;
        int k = kk * 32 + (lane >> 4) * 8 + j;
        int n = t * 16 + (lane & 15);
        Wn_shuf[id] = cvt_bf16(Wn[k * HID + n]);
    }
}

// --- counting sort of edges by dst ---
__global__ void hist_kernel(const int* __restrict__ dst, int* __restrict__ bend) {
    int e = blockIdx.x * blockDim.x + threadIdx.x;
    if (e < N_EDGES) atomicAdd(&bend[dst[e]], 1);
}

#define SCAN_T 1024
__global__ __launch_bounds__(1024) void scan_kernel(int* __restrict__ bend) {
    __shared__ int part[SCAN_T];
    int t = threadIdx.x;
    const int chunk = (N_NODES + SCAN_T - 1) / SCAN_T;  // 49
    int lo = t * chunk;
    int hi = lo + chunk;
    if (hi > N_NODES) hi = N_NODES;
    if (lo > N_NODES) lo = N_NODES;
    int s = 0;
    for (int i = lo; i < hi; ++i) s += bend[i];
    part[t] = s;
    __syncthreads();
    for (int off = 1; off < SCAN_T; off <<= 1) {
        int v = 0;
        if (t >= off) v = part[t - off];
        __syncthreads();
        if (t >= off) part[t] += v;
        __syncthreads();
    }
    int excl = (t == 0) ? 0 : part[t - 1];
    for (int i = lo; i < hi; ++i) {
        int v = bend[i];
        bend[i] = excl;
        excl += v;
    }
}

__global__ void scatter_kernel(const int* __restrict__ dst, int* __restrict__ bend,
                               int* __restrict__ order, int* __restrict__ rank) {
    int e = blockIdx.x * blockDim.x + threadIdx.x;
    if (e < N_EDGES) {
        int pos = atomicAdd(&bend[dst[e]], 1);
        order[pos] = e;
        rank[e] = pos;
    }
}

// --- edge kernel: per wave, 32 edges x 128 cols. Natural edge order.
// out1[e] = relu(concat(nfeats[src], efeats[e], nfeats[dst]) @ We + be) + efeats[e]
// if msorted: also msorted[rank[e]] = relu(...)   (dst-sorted message store)
__global__ __launch_bounds__(128) void edge_kernel(
    const float* __restrict__ nfeats, const float* __restrict__ efeats,
    const int* __restrict__ src, const int* __restrict__ dst,
    const unsigned short* __restrict__ We_shuf, const float* __restrict__ be,
    float* __restrict__ out1, float* __restrict__ msorted, const int* __restrict__ rank) {
    __shared__ float ef_lds[2][32 * 128];  // 16 KB per wave
    int w = threadIdx.x >> 6;
    int wid = blockIdx.x * 2 + w;
    int lane = threadIdx.x & 63;
    int e0 = wid * 32;
    int m = lane & 15, quad = lane >> 4;
    float* ef = &ef_lds[w][0];

    // stage 32 efeats rows into LDS (coalesced source, swizzled chunk order)
#pragma unroll
    for (int i = 0; i < 16; ++i) {
        int row = 2 * i + (lane >> 5);
        int c16 = (lane & 31) ^ (row & 7);
        gload16(efeats + (size_t)(e0 + row) * HID + c16 * 4, ef + i * 256);
    }

    int r0 = e0 + m, r1 = e0 + 16 + m;
    const float* s0 = nfeats + (size_t)src[r0] * HID;
    const float* s1 = nfeats + (size_t)src[r1] * HID;
    const float* d0 = nfeats + (size_t)dst[r0] * HID;
    const float* d1 = nfeats + (size_t)dst[r1] * HID;

    f32x4 acc[2][8];
#pragma unroll
    for (int mi = 0; mi < 2; ++mi)
#pragma unroll
        for (int t = 0; t < 8; ++t) acc[mi][t] = (f32x4){0.f, 0.f, 0.f, 0.f};

    const bf16x8* W = (const bf16x8*)We_shuf;

    // seg0: k in [0,128) from nfeats[src]
#pragma unroll
    for (int kk = 0; kk < 4; ++kk) {
        int off = kk * 32 + quad * 8;
        bf16x8 a0 = load_row8_bf16(s0 + off);
        bf16x8 a1 = load_row8_bf16(s1 + off);
#pragma unroll
        for (int t = 0; t < 8; ++t) {
            bf16x8 b = W[(kk * 8 + t) * 64 + lane];
            acc[0][t] = __builtin_amdgcn_mfma_f32_16x16x32_bf16(a0, b, acc[0][t], 0, 0, 0);
            acc[1][t] = __builtin_amdgcn_mfma_f32_16x16x32_bf16(a1, b, acc[1][t], 0, 0, 0);
        }
    }
    // seg2: k in [256,384) from nfeats[dst]
#pragma unroll
    for (int kk = 8; kk < 12; ++kk) {
        int off = (kk - 8) * 32 + quad * 8;
        bf16x8 a0 = load_row8_bf16(d0 + off);
        bf16x8 a1 = load_row8_bf16(d1 + off);
#pragma unroll
        for (int t = 0; t < 8; ++t) {
            bf16x8 b = W[(kk * 8 + t) * 64 + lane];
            acc[0][t] = __builtin_amdgcn_mfma_f32_16x16x32_bf16(a0, b, acc[0][t], 0, 0, 0);
            acc[1][t] = __builtin_amdgcn_mfma_f32_16x16x32_bf16(a1, b, acc[1][t], 0, 0, 0);
        }
    }

    // all global_load_lds (and prior gathers) complete
    asm volatile("s_waitcnt vmcnt(0)" ::: "memory");

    // seg1: k in [128,256) from LDS efeats
#pragma unroll
    for (int kk = 4; kk < 8; ++kk) {
        int c16 = (kk - 4) * 8 + quad * 2;
        bf16x8 a0 = load_frag_lds(ef, m, c16);
        bf16x8 a1 = load_frag_lds(ef, 16 + m, c16);
#pragma unroll
        for (int t = 0; t < 8; ++t) {
            bf16x8 b = W[(kk * 8 + t) * 64 + lane];
            acc[0][t] = __builtin_amdgcn_mfma_f32_16x16x32_bf16(a0, b, acc[0][t], 0, 0, 0);
            acc[1][t] = __builtin_amdgcn_mfma_f32_16x16x32_bf16(a1, b, acc[1][t], 0, 0, 0);
        }
    }

    float bev[8];
#pragma unroll
    for (int t = 0; t < 8; ++t) bev[t] = be[t * 16 + m];

    // epilogue: C/D layout col = lane&15, row = quad*4 + reg
    if (msorted) {
#pragma unroll
        for (int mi = 0; mi < 2; ++mi) {
#pragma unroll
            for (int r = 0; r < 4; ++r) {
                int lrow = mi * 16 + quad * 4 + r;
                int e = e0 + lrow;
                float* o = out1 + (size_t)e * HID;
                float* ms = msorted + (size_t)rank[e] * HID;
#pragma unroll
                for (int t = 0; t < 8; ++t) {
                    int n = t * 16 + m;
                    float v = fmaxf(acc[mi][t][r] + bev[t], 0.0f);
                    o[n] = v + lds_ef_read(ef, lrow, n);
                    ms[n] = v;
                }
            }
        }
    } else {
#pragma unroll
        for (int mi = 0; mi < 2; ++mi) {
#pragma unroll
            for (int r = 0; r < 4; ++r) {
                int lrow = mi * 16 + quad * 4 + r;
                int e = e0 + lrow;
                float* o = out1 + (size_t)e * HID;
#pragma unroll
                for (int t = 0; t < 8; ++t) {
                    int n = t * 16 + m;
                    float v = fmaxf(acc[mi][t][r] + bev[t], 0.0f);
                    o[n] = v + lds_ef_read(ef, lrow, n);
                }
            }
        }
    }
}

// --- gather (sorted): node n mean-reduces consecutive rows [start,end) of msorted.
__global__ __launch_bounds__(256) void gather_sorted(
    const float* __restrict__ msorted, const int* __restrict__ bend,
    float* __restrict__ h) {
    int wid = blockIdx.x * 4 + (threadIdx.x >> 6);
    if (wid >= N_NODES) return;
    int lane = threadIdx.x & 63;
    int start = (wid == 0) ? 0 : bend[wid - 1];
    int end = bend[wid];
    const float2* base = (const float2*)msorted;
    float ax = 0.f, ay = 0.f;
    int j = start;
    for (; j + 4 <= end; j += 4) {
        float2 v0 = base[(size_t)(j + 0) * 64 + lane];
        float2 v1 = base[(size_t)(j + 1) * 64 + lane];
        float2 v2 = base[(size_t)(j + 2) * 64 + lane];
        float2 v3 = base[(size_t)(j + 3) * 64 + lane];
        ax += (v0.x + v1.x) + (v2.x + v3.x);
        ay += (v0.y + v1.y) + (v2.y + v3.y);
    }
    for (; j < end; ++j) {
        float2 v = base[(size_t)j * 64 + lane];
        ax += v.x;
        ay += v.y;
    }
    int deg = end - start;
    float inv = (deg > 0) ? 1.0f / (float)deg : 0.0f;
    float2 r;
    r.x = ax * inv;
    r.y = ay * inv;
    ((float2*)(h + (size_t)wid * HID))[lane] = r;
}

// --- gather (fallback, round-1 style): scattered re-read of out1/efeats via order[]
__global__ __launch_bounds__(256) void gather_kernel(
    const float* __restrict__ out1, const float* __restrict__ efeats,
    const int* __restrict__ order, const int* __restrict__ bend,
    float* __restrict__ h) {
    int wid = blockIdx.x * 4 + (threadIdx.x >> 6);
    if (wid >= N_NODES) return;
    int lane = threadIdx.x & 63;
    int start = (wid == 0) ? 0 : bend[wid - 1];
    int end = bend[wid];
    float ax = 0.0f, ay = 0.0f;
    int j = start;
    for (; j + 2 <= end; j += 2) {
        int ea = order[j], eb = order[j + 1];
        float2 o1 = ((const float2*)(out1 + (size_t)ea * HID))[lane];
        float2 f1 = ((const float2*)(efeats + (size_t)ea * HID))[lane];
        float2 o2 = ((const float2*)(out1 + (size_t)eb * HID))[lane];
        float2 f2 = ((const float2*)(efeats + (size_t)eb * HID))[lane];
        ax += (o1.x - f1.x) + (o2.x - f2.x);
        ay += (o1.y - f1.y) + (o2.y - f2.y);
    }
    if (j < end) {
        int ea = order[j];
        float2 o1 = ((const float2*)(out1 + (size_t)ea * HID))[lane];
        float2 f1 = ((const float2*)(efeats + (size_t)ea * HID))[lane];
        ax += o1.x - f1.x;
        ay += o1.y - f1.y;
    }
    int deg = end - start;
    float inv = (deg > 0) ? 1.0f / (float)deg : 0.0f;
    float2 r;
    r.x = ax * inv;
    r.y = ay * inv;
    ((float2*)(h + (size_t)wid * HID))[lane] = r;
}

// --- node kernel: per wave, 16 nodes x 128 cols.
__global__ __launch_bounds__(256) void node_kernel(
    const float* __restrict__ nfeats, const unsigned short* __restrict__ Wn_shuf,
    const float* __restrict__ bn, const float* __restrict__ h,
    float* __restrict__ out0) {
    int wid = blockIdx.x * 4 + (threadIdx.x >> 6);
    int n0 = wid * 16;
    if (n0 >= N_NODES) return;
    int lane = threadIdx.x & 63;
    int m = lane & 15, quad = lane >> 4;
    int row = n0 + m;
    const float* pn = nfeats + (size_t)row * HID;
    const float* ph = h + (size_t)row * HID;

    f32x4 acc[8];
#pragma unroll
    for (int t = 0; t < 8; ++t) acc[t] = (f32x4){0.f, 0.f, 0.f, 0.f};

    const bf16x8* W = (const bf16x8*)Wn_shuf;

#pragma unroll
    for (int kk = 0; kk < 8; ++kk) {
        int k = kk * 32 + quad * 8;
        bf16x8 a = (k < 128) ? load_row8_bf16(pn + k)
                             : load_row8_bf16(ph + (k - 128));
#pragma unroll
        for (int t = 0; t < 8; ++t) {
            bf16x8 b = W[(kk * 8 + t) * 64 + lane];
            acc[t] = __builtin_amdgcn_mfma_f32_16x16x32_bf16(a, b, acc[t], 0, 0, 0);
        }
    }

    float bnv[8];
#pragma unroll
    for (int t = 0; t < 8; ++t) bnv[t] = bn[t * 16 + m];

#pragma unroll
    for (int r = 0; r < 4; ++r) {
        int rw = n0 + quad * 4 + r;
        const float* nf = nfeats + (size_t)rw * HID;
        float* o = out0 + (size_t)rw * HID;
#pragma unroll
        for (int t = 0; t < 8; ++t) {
            int n = t * 16 + m;
            float v = fmaxf(acc[t][r] + bnv[t], 0.0f);
            o[n] = v + nf[n];
        }
    }
}

extern "C" void kernel_launch(void* const* d_in, const int* in_sizes, int n_in,
                              void* d_out, int out_size, void* d_ws, size_t ws_size,
                              hipStream_t stream) {
    const float* nfeats = (const float*)d_in[0];
    const float* efeats = (const float*)d_in[1];
    const int* src = (const int*)d_in[2];
    const int* dst = (const int*)d_in[3];
    const float* We = (const float*)d_in[4];
    const float* be = (const float*)d_in[5];
    const float* Wn = (const float*)d_in[6];
    const float* bn = (const float*)d_in[7];

    float* out0 = (float*)d_out;                       // [N_NODES, HID]
    float* out1 = out0 + (size_t)N_NODES * HID;        // [N_EDGES, HID]

    // sort scratch in the out0 region (dead until node_kernel, which runs last):
    // rank[E] + order[E] + bend[N] = 6.6 MB << 25.6 MB
    int* rank = (int*)d_out;
    int* order = rank + N_EDGES;
    int* bend = order + N_EDGES;

    // workspace: h (N*H fp32) | We_shuf | Wn_shuf | [msorted (E*H fp32) if it fits]
    float* h = (float*)d_ws;
    unsigned short* We_shuf = (unsigned short*)(h + (size_t)N_NODES * HID);
    unsigned short* Wn_shuf = We_shuf + WE_SHUF_ELEMS;
    size_t base_bytes = (size_t)N_NODES * HID * 4 + (size_t)(WE_SHUF_ELEMS + WN_SHUF_ELEMS) * 2;
    // 25,763,840 (64B aligned)
    size_t need = base_bytes + (size_t)N_EDGES * HID * 4;
    float* msorted = (ws_size >= need) ? (float*)((char*)d_ws + base_bytes) : nullptr;

    hipMemsetAsync(bend, 0, N_NODES * sizeof(int), stream);

    prep_kernel<<<(WE_SHUF_ELEMS + WN_SHUF_ELEMS) / 256, 256, 0, stream>>>(We, Wn, We_shuf, Wn_shuf);

    hist_kernel<<<N_EDGES / 256, 256, 0, stream>>>(dst, bend);
    scan_kernel<<<1, SCAN_T, 0, stream>>>(bend);
    scatter_kernel<<<N_EDGES / 256, 256, 0, stream>>>(dst, bend, order, rank);

    // 800000 edges / 32 per wave = 25000 waves / 2 per block = 12500 blocks
    edge_kernel<<<12500, 128, 0, stream>>>(nfeats, efeats, src, dst, We_shuf, be,
                                           out1, msorted, rank);

    if (msorted) {
        gather_sorted<<<12500, 256, 0, stream>>>(msorted, bend, h);
    } else {
        gather_kernel<<<12500, 256, 0, stream>>>(out1, efeats, order, bend, h);
    }

    node_kernel<<<782, 256, 0, stream>>>(nfeats, Wn_shuf, bn, h, out0);
}

// Round 3
// 1072.599 us; speedup vs baseline: 1.3221x; 1.1635x over previous
//
#include <hip/hip_runtime.h>
#include <stdint.h>

#define N_NODES 50000
#define N_EDGES 800000
#define HID 128

typedef __attribute__((ext_vector_type(8))) short bf16x8;
typedef __attribute__((ext_vector_type(4))) float f32x4;

// round-half-up fp32 -> bf16 pair, packed into one u32 (x = low half)
__device__ inline uint32_t pack_bf16(float x, float y) {
    uint32_t a = __builtin_bit_cast(uint32_t, x) + 0x8000u;
    uint32_t b = __builtin_bit_cast(uint32_t, y) + 0x8000u;
    return (b & 0xffff0000u) | (a >> 16);
}

__device__ inline unsigned short cvt_bf16(float x) {
    return (unsigned short)((__builtin_bit_cast(uint32_t, x) + 0x8000u) >> 16);
}

// 8 consecutive fp32 (32B aligned) -> bf16x8 fragment
__device__ inline bf16x8 load_row8_bf16(const float* p) {
    const float4* q = (const float4*)p;
    float4 u = q[0], v = q[1];
    union { bf16x8 v8; uint32_t u32[4]; } r;
    r.u32[0] = pack_bf16(u.x, u.y);
    r.u32[1] = pack_bf16(u.z, u.w);
    r.u32[2] = pack_bf16(v.x, v.y);
    r.u32[3] = pack_bf16(v.z, v.w);
    return r.v8;
}

// scaled variant (node kernel: h = sums * inv_deg)
__device__ inline bf16x8 load_row8_bf16_scaled(const float* p, float s) {
    const float4* q = (const float4*)p;
    float4 u = q[0], v = q[1];
    union { bf16x8 v8; uint32_t u32[4]; } r;
    r.u32[0] = pack_bf16(u.x * s, u.y * s);
    r.u32[1] = pack_bf16(u.z * s, u.w * s);
    r.u32[2] = pack_bf16(v.x * s, v.y * s);
    r.u32[3] = pack_bf16(v.z * s, v.w * s);
    return r.v8;
}

// async 16B global->LDS (lane l writes lds_base + l*16; source per-lane)
__device__ inline void gload16(const float* g, float* l) {
    __builtin_amdgcn_global_load_lds(
        (const __attribute__((address_space(1))) void*)g,
        (__attribute__((address_space(3))) void*)l, 16, 0, 0);
}

// LDS efeats tile: logical (row, 16B-chunk c) stored at chunk index c ^ (row&7).
// Same swizzle at stage-source, fragment read, and epilogue read (both-sides rule).
__device__ inline float lds_ef_read(const float* ef, int row, int n) {
    return ef[row * 128 + ((((n >> 2) ^ (row & 7)) << 2) | (n & 3))];
}

__device__ inline bf16x8 load_frag_lds(const float* ef, int row, int c16) {
    int s = row & 7;
    float4 u = *(const float4*)(ef + row * 128 + ((c16 ^ s) << 2));
    float4 v = *(const float4*)(ef + row * 128 + (((c16 + 1) ^ s) << 2));
    union { bf16x8 v8; uint32_t u32[4]; } r;
    r.u32[0] = pack_bf16(u.x, u.y);
    r.u32[1] = pack_bf16(u.z, u.w);
    r.u32[2] = pack_bf16(v.x, v.y);
    r.u32[3] = pack_bf16(v.z, v.w);
    return r.v8;
}

// --- prep: shuffle We (384x128) and Wn (256x128) fp32 -> bf16 in MFMA
// B-fragment order: frag index (kk, t), lane l holds B[kk*32 + (l>>4)*8 + j][t*16 + (l&15)]
#define WE_SHUF_ELEMS (12 * 8 * 64 * 8)  // 49152
#define WN_SHUF_ELEMS (8 * 8 * 64 * 8)   // 32768
__global__ void prep_kernel(const float* __restrict__ We, const float* __restrict__ Wn,
                            unsigned short* __restrict__ We_shuf,
                            unsigned short* __restrict__ Wn_shuf) {
    int tid = blockIdx.x * blockDim.x + threadIdx.x;
    if (tid < WE_SHUF_ELEMS) {
        int j = tid & 7, lane = (tid >> 3) & 63, tt = tid >> 9;
        int t = tt & 7, kk = tt >> 3;
        int k = kk * 32 + (lane >> 4) * 8 + j;
        int n = t * 16 + (lane & 15);
        We_shuf[tid] = cvt_bf16(We[k * HID + n]);
    } else if (tid < WE_SHUF_ELEMS + WN_SHUF_ELEMS) {
        int id = tid - WE_SHUF_ELEMS;
        int j = id & 7, lane = (id >> 3) & 63, tt = id >> 9;
        int t = tt & 7, kk = tt >> 3;
        int k = kk * 32 + (lane >> 4) * 8 + j;
        int n = t * 16 + (lane & 15);
        Wn_shuf[id] = cvt_bf16(Wn[k * HID + n]);
    }
}

// --- counting sort of edges by dst ---
__global__ void hist_kernel(const int* __restrict__ dst, int* __restrict__ bend) {
    int e = blockIdx.x * blockDim.x + threadIdx.x;
    if (e < N_EDGES) atomicAdd(&bend[dst[e]], 1);
}

#define SCAN_T 1024
__global__ __launch_bounds__(1024) void scan_kernel(int* __restrict__ bend) {
    __shared__ int part[SCAN_T];
    int t = threadIdx.x;
    const int chunk = (N_NODES + SCAN_T - 1) / SCAN_T;  // 49
    int lo = t * chunk;
    int hi = lo + chunk;
    if (hi > N_NODES) hi = N_NODES;
    if (lo > N_NODES) lo = N_NODES;
    int s = 0;
    for (int i = lo; i < hi; ++i) s += bend[i];
    part[t] = s;
    __syncthreads();
    for (int off = 1; off < SCAN_T; off <<= 1) {
        int v = 0;
        if (t >= off) v = part[t - off];
        __syncthreads();
        if (t >= off) part[t] += v;
        __syncthreads();
    }
    int excl = (t == 0) ? 0 : part[t - 1];
    for (int i = lo; i < hi; ++i) {
        int v = bend[i];
        bend[i] = excl;
        excl += v;
    }
}

__global__ void scatter_kernel(const int* __restrict__ dst, int* __restrict__ bend,
                               int* __restrict__ order) {
    int e = blockIdx.x * blockDim.x + threadIdx.x;
    if (e < N_EDGES) {
        int pos = atomicAdd(&bend[dst[e]], 1);
        order[pos] = e;
    }
}

// --- edge kernel (dst-sorted order): per wave, 32 sorted positions x 128 cols.
// v = relu(concat(nfeats[src], efeats[e], nfeats[dst]) @ We + be)
// out1[e] = v + efeats[e];  sums[dst] += segmented in-register reduce of v.
__global__ __launch_bounds__(128) void edge_kernel(
    const float* __restrict__ nfeats, const float* __restrict__ efeats,
    const int* __restrict__ src, const int* __restrict__ dst,
    const int* __restrict__ order,
    const unsigned short* __restrict__ We_shuf, const float* __restrict__ be,
    float* __restrict__ out1, float* __restrict__ sums) {
    __shared__ float ef_lds[2][32 * 128];  // 16 KB per wave
    int w = threadIdx.x >> 6;
    int wid = blockIdx.x * 2 + w;
    int lane = threadIdx.x & 63;
    int e0 = wid * 32;
    int m = lane & 15, quad = lane >> 4;
    float* ef = &ef_lds[w][0];

    // lane i<32 owns sorted position e0+i
    int i = lane;
    int e_i = 0, d_i = 0;
    if (i < 32) {
        e_i = order[e0 + i];
        d_i = dst[e_i];
    }

    // stage 32 efeats rows into LDS (per-lane scattered source, swizzled chunks)
#pragma unroll
    for (int it = 0; it < 16; ++it) {
        int row = 2 * it + (lane >> 5);
        int er = __shfl(e_i, row);
        int c16 = (lane & 31) ^ (row & 7);
        gload16(efeats + (size_t)er * HID + c16 * 4, ef + it * 256);
    }

    // A-operand edges for rows m and 16+m
    int ea = __shfl(e_i, m), eb = __shfl(e_i, 16 + m);
    int da = __shfl(d_i, m), db = __shfl(d_i, 16 + m);
    const float* s0 = nfeats + (size_t)src[ea] * HID;
    const float* s1 = nfeats + (size_t)src[eb] * HID;
    const float* d0 = nfeats + (size_t)da * HID;
    const float* d1 = nfeats + (size_t)db * HID;

    f32x4 acc[2][8];
#pragma unroll
    for (int mi = 0; mi < 2; ++mi)
#pragma unroll
        for (int t = 0; t < 8; ++t) acc[mi][t] = (f32x4){0.f, 0.f, 0.f, 0.f};

    const bf16x8* W = (const bf16x8*)We_shuf;

    // seg0: k in [0,128) from nfeats[src]
#pragma unroll
    for (int kk = 0; kk < 4; ++kk) {
        int off = kk * 32 + quad * 8;
        bf16x8 a0 = load_row8_bf16(s0 + off);
        bf16x8 a1 = load_row8_bf16(s1 + off);
#pragma unroll
        for (int t = 0; t < 8; ++t) {
            bf16x8 b = W[(kk * 8 + t) * 64 + lane];
            acc[0][t] = __builtin_amdgcn_mfma_f32_16x16x32_bf16(a0, b, acc[0][t], 0, 0, 0);
            acc[1][t] = __builtin_amdgcn_mfma_f32_16x16x32_bf16(a1, b, acc[1][t], 0, 0, 0);
        }
    }
    // seg2: k in [256,384) from nfeats[dst] (mostly broadcast across lanes: sorted)
#pragma unroll
    for (int kk = 8; kk < 12; ++kk) {
        int off = (kk - 8) * 32 + quad * 8;
        bf16x8 a0 = load_row8_bf16(d0 + off);
        bf16x8 a1 = load_row8_bf16(d1 + off);
#pragma unroll
        for (int t = 0; t < 8; ++t) {
            bf16x8 b = W[(kk * 8 + t) * 64 + lane];
            acc[0][t] = __builtin_amdgcn_mfma_f32_16x16x32_bf16(a0, b, acc[0][t], 0, 0, 0);
            acc[1][t] = __builtin_amdgcn_mfma_f32_16x16x32_bf16(a1, b, acc[1][t], 0, 0, 0);
        }
    }

    // all global_load_lds complete
    asm volatile("s_waitcnt vmcnt(0)" ::: "memory");

    // seg1: k in [128,256) from LDS efeats
#pragma unroll
    for (int kk = 4; kk < 8; ++kk) {
        int c16 = (kk - 4) * 8 + quad * 2;
        bf16x8 a0 = load_frag_lds(ef, m, c16);
        bf16x8 a1 = load_frag_lds(ef, 16 + m, c16);
#pragma unroll
        for (int t = 0; t < 8; ++t) {
            bf16x8 b = W[(kk * 8 + t) * 64 + lane];
            acc[0][t] = __builtin_amdgcn_mfma_f32_16x16x32_bf16(a0, b, acc[0][t], 0, 0, 0);
            acc[1][t] = __builtin_amdgcn_mfma_f32_16x16x32_bf16(a1, b, acc[1][t], 0, 0, 0);
        }
    }

    float bev[8];
#pragma unroll
    for (int t = 0; t < 8; ++t) bev[t] = be[t * 16 + m];

    // epilogue: relu into acc (kept for reduction), out1[e] = v + efeats[e]
    // C/D layout: col = t*16 + m, window row = mi*16 + quad*4 + r
#pragma unroll
    for (int mi = 0; mi < 2; ++mi) {
#pragma unroll
        for (int r = 0; r < 4; ++r) {
            int lrow = mi * 16 + quad * 4 + r;
            int e = __shfl(e_i, lrow);
            float* o = out1 + (size_t)e * HID;
#pragma unroll
            for (int t = 0; t < 8; ++t) {
                int n = t * 16 + m;
                float v = fmaxf(acc[mi][t][r] + bev[t], 0.0f);
                acc[mi][t][r] = v;
                o[n] = v + lds_ef_read(ef, lrow, n);
            }
        }
    }

    // segmented reduction over sorted dst runs
    int dprev = __shfl(d_i, (i == 0) ? 0 : i - 1);
    bool head = (i < 32) && (i == 0 || d_i != dprev);
    unsigned long long mask = __ballot(head);
    while (mask) {
        int a = __builtin_ctzll(mask);
        mask &= mask - 1;
        int b = mask ? __builtin_ctzll(mask) : 32;
        int nd = __shfl(d_i, a);
        float tot[8];
#pragma unroll
        for (int t = 0; t < 8; ++t) tot[t] = 0.f;
#pragma unroll
        for (int mi = 0; mi < 2; ++mi) {
#pragma unroll
            for (int r = 0; r < 4; ++r) {
                int lrow = mi * 16 + quad * 4 + r;
                bool in = (lrow >= a) && (lrow < b);
#pragma unroll
                for (int t = 0; t < 8; ++t) tot[t] += in ? acc[mi][t][r] : 0.0f;
            }
        }
#pragma unroll
        for (int t = 0; t < 8; ++t) {
            tot[t] += __shfl_xor(tot[t], 16);
            tot[t] += __shfl_xor(tot[t], 32);
        }
        float* srow = sums + (size_t)nd * HID;
#pragma unroll
        for (int q = 0; q < 2; ++q) {
            int t = quad + q * 4;
            atomicAdd(&srow[t * 16 + m], tot[t]);
        }
    }
}

// --- node kernel: per wave, 16 nodes x 128 cols.
// h = sums/max(deg,1) with deg from bend diffs; out0 = relu(concat(nfeats,h)@Wn+bn)+nfeats
__global__ __launch_bounds__(256) void node_kernel(
    const float* __restrict__ nfeats, const unsigned short* __restrict__ Wn_shuf,
    const float* __restrict__ bn, const float* __restrict__ sums,
    const int* __restrict__ bend, float* __restrict__ out0) {
    int wid = blockIdx.x * 4 + (threadIdx.x >> 6);
    int n0 = wid * 16;
    if (n0 >= N_NODES) return;
    int lane = threadIdx.x & 63;
    int m = lane & 15, quad = lane >> 4;
    int row = n0 + m;
    int end = bend[row];
    int start = (row == 0) ? 0 : bend[row - 1];
    float inv = 1.0f / fmaxf((float)(end - start), 1.0f);
    const float* pn = nfeats + (size_t)row * HID;
    const float* ps = sums + (size_t)row * HID;

    f32x4 acc[8];
#pragma unroll
    for (int t = 0; t < 8; ++t) acc[t] = (f32x4){0.f, 0.f, 0.f, 0.f};

    const bf16x8* W = (const bf16x8*)Wn_shuf;

#pragma unroll
    for (int kk = 0; kk < 8; ++kk) {
        int k = kk * 32 + quad * 8;
        bf16x8 a = (k < 128) ? load_row8_bf16(pn + k)
                             : load_row8_bf16_scaled(ps + (k - 128), inv);
#pragma unroll
        for (int t = 0; t < 8; ++t) {
            bf16x8 b = W[(kk * 8 + t) * 64 + lane];
            acc[t] = __builtin_amdgcn_mfma_f32_16x16x32_bf16(a, b, acc[t], 0, 0, 0);
        }
    }

    float bnv[8];
#pragma unroll
    for (int t = 0; t < 8; ++t) bnv[t] = bn[t * 16 + m];

#pragma unroll
    for (int r = 0; r < 4; ++r) {
        int rw = n0 + quad * 4 + r;
        const float* nf = nfeats + (size_t)rw * HID;
        float* o = out0 + (size_t)rw * HID;
#pragma unroll
        for (int t = 0; t < 8; ++t) {
            int n = t * 16 + m;
            float v = fmaxf(acc[t][r] + bnv[t], 0.0f);
            o[n] = v + nf[n];
        }
    }
}

extern "C" void kernel_launch(void* const* d_in, const int* in_sizes, int n_in,
                              void* d_out, int out_size, void* d_ws, size_t ws_size,
                              hipStream_t stream) {
    const float* nfeats = (const float*)d_in[0];
    const float* efeats = (const float*)d_in[1];
    const int* src = (const int*)d_in[2];
    const int* dst = (const int*)d_in[3];
    const float* We = (const float*)d_in[4];
    const float* be = (const float*)d_in[5];
    const float* Wn = (const float*)d_in[6];
    const float* bn = (const float*)d_in[7];

    float* out0 = (float*)d_out;                       // [N_NODES, HID]
    float* out1 = out0 + (size_t)N_NODES * HID;        // [N_EDGES, HID]

    // order[] lives in the out0 region (dead until node_kernel, which runs last
    // and only starts after edge_kernel has fully consumed order): 3.2 MB.
    int* order = (int*)d_out;

    // workspace: sums (N*H fp32) | We_shuf | Wn_shuf | bend[N]
    float* sums = (float*)d_ws;
    unsigned short* We_shuf = (unsigned short*)(sums + (size_t)N_NODES * HID);
    unsigned short* Wn_shuf = We_shuf + WE_SHUF_ELEMS;
    int* bend = (int*)(Wn_shuf + WN_SHUF_ELEMS);  // byte off 25,763,840

    // zero sums (+shuf region, harmless: prep overwrites) + bend in one memset
    hipMemsetAsync(d_ws, 0,
                   (size_t)N_NODES * HID * 4 + (WE_SHUF_ELEMS + WN_SHUF_ELEMS) * 2 +
                       N_NODES * sizeof(int),
                   stream);

    prep_kernel<<<(WE_SHUF_ELEMS + WN_SHUF_ELEMS) / 256, 256, 0, stream>>>(We, Wn, We_shuf, Wn_shuf);

    hist_kernel<<<N_EDGES / 256, 256, 0, stream>>>(dst, bend);
    scan_kernel<<<1, SCAN_T, 0, stream>>>(bend);
    scatter_kernel<<<N_EDGES / 256, 256, 0, stream>>>(dst, bend, order);

    // 800000 positions / 32 per wave = 25000 waves / 2 per block = 12500 blocks
    edge_kernel<<<12500, 128, 0, stream>>>(nfeats, efeats, src, dst, order,
                                           We_shuf, be, out1, sums);

    // 50000 nodes / 16 per wave = 3125 waves -> 782 blocks (guarded)
    node_kernel<<<782, 256, 0, stream>>>(nfeats, Wn_shuf, bn, sums, bend, out0);
}

// Round 4
// 1038.707 us; speedup vs baseline: 1.3652x; 1.0326x over previous
//
#include <hip/hip_runtime.h>
#include <stdint.h>

#define N_NODES 50000
#define N_EDGES 800000
#define HID 128

typedef __attribute__((ext_vector_type(8))) short bf16x8;
typedef __attribute__((ext_vector_type(4))) float f32x4;

// round-half-up fp32 -> bf16 pair, packed into one u32 (x = low half)
__device__ inline uint32_t pack_bf16(float x, float y) {
    uint32_t a = __builtin_bit_cast(uint32_t, x) + 0x8000u;
    uint32_t b = __builtin_bit_cast(uint32_t, y) + 0x8000u;
    return (b & 0xffff0000u) | (a >> 16);
}

__device__ inline unsigned short cvt_bf16(float x) {
    return (unsigned short)((__builtin_bit_cast(uint32_t, x) + 0x8000u) >> 16);
}

// 8 consecutive fp32 (32B aligned) -> bf16x8 fragment
__device__ inline bf16x8 load_row8_bf16(const float* p) {
    const float4* q = (const float4*)p;
    float4 u = q[0], v = q[1];
    union { bf16x8 v8; uint32_t u32[4]; } r;
    r.u32[0] = pack_bf16(u.x, u.y);
    r.u32[1] = pack_bf16(u.z, u.w);
    r.u32[2] = pack_bf16(v.x, v.y);
    r.u32[3] = pack_bf16(v.z, v.w);
    return r.v8;
}

// scaled variant (node kernel: h = sums * inv_deg)
__device__ inline bf16x8 load_row8_bf16_scaled(const float* p, float s) {
    const float4* q = (const float4*)p;
    float4 u = q[0], v = q[1];
    union { bf16x8 v8; uint32_t u32[4]; } r;
    r.u32[0] = pack_bf16(u.x * s, u.y * s);
    r.u32[1] = pack_bf16(u.z * s, u.w * s);
    r.u32[2] = pack_bf16(v.x * s, v.y * s);
    r.u32[3] = pack_bf16(v.z * s, v.w * s);
    return r.v8;
}

// async 16B global->LDS (lane l writes lds_base + l*16; source per-lane)
__device__ inline void gload16(const float* g, float* l) {
    __builtin_amdgcn_global_load_lds(
        (const __attribute__((address_space(1))) void*)g,
        (__attribute__((address_space(3))) void*)l, 16, 0, 0);
}

// LDS efeats tile: logical (row, 16B-chunk c) stored at chunk index c ^ (row&7).
// Same swizzle at stage-source, fragment read, and epilogue read (both-sides rule).
__device__ inline float lds_ef_read(const float* ef, int row, int n) {
    return ef[row * 128 + ((((n >> 2) ^ (row & 7)) << 2) | (n & 3))];
}

__device__ inline bf16x8 load_frag_lds(const float* ef, int row, int c16) {
    int s = row & 7;
    float4 u = *(const float4*)(ef + row * 128 + ((c16 ^ s) << 2));
    float4 v = *(const float4*)(ef + row * 128 + (((c16 + 1) ^ s) << 2));
    union { bf16x8 v8; uint32_t u32[4]; } r;
    r.u32[0] = pack_bf16(u.x, u.y);
    r.u32[1] = pack_bf16(u.z, u.w);
    r.u32[2] = pack_bf16(v.x, v.y);
    r.u32[3] = pack_bf16(v.z, v.w);
    return r.v8;
}

// --- prep: shuffle We (384x128) and Wn (256x128) fp32 -> bf16 in MFMA
// B-fragment order: frag index (kk, t), lane l holds B[kk*32 + (l>>4)*8 + j][t*16 + (l&15)]
#define WE_SHUF_ELEMS (12 * 8 * 64 * 8)  // 49152
#define WN_SHUF_ELEMS (8 * 8 * 64 * 8)   // 32768
__global__ void prep_kernel(const float* __restrict__ We, const float* __restrict__ Wn,
                            unsigned short* __restrict__ We_shuf,
                            unsigned short* __restrict__ Wn_shuf) {
    int tid = blockIdx.x * blockDim.x + threadIdx.x;
    if (tid < WE_SHUF_ELEMS) {
        int j = tid & 7, lane = (tid >> 3) & 63, tt = tid >> 9;
        int t = tt & 7, kk = tt >> 3;
        int k = kk * 32 + (lane >> 4) * 8 + j;
        int n = t * 16 + (lane & 15);
        We_shuf[tid] = cvt_bf16(We[k * HID + n]);
    } else if (tid < WE_SHUF_ELEMS + WN_SHUF_ELEMS) {
        int id = tid - WE_SHUF_ELEMS;
        int j = id & 7, lane = (id >> 3) & 63, tt = id >> 9;
        int t = tt & 7, kk = tt >> 3;
        int k = kk * 32 + (lane >> 4) * 8 + j;
        int n = t * 16 + (lane & 15);
        Wn_shuf[id] = cvt_bf16(Wn[k * HID + n]);
    }
}

// --- counting sort of edges by dst ---
__global__ void hist_kernel(const int* __restrict__ dst, int* __restrict__ bend) {
    int e = blockIdx.x * blockDim.x + threadIdx.x;
    if (e < N_EDGES) atomicAdd(&bend[dst[e]], 1);
}

// 3-phase parallel exclusive scan of bend[N_NODES] (replaces the 1-block serial scan)
#define SCB 1024
#define SCAN_NBLK ((N_NODES + SCB - 1) / SCB)  // 49
__global__ __launch_bounds__(SCB) void scan1_kernel(const int* __restrict__ bend,
                                                    int* __restrict__ partial) {
    __shared__ int red[SCB];
    int t = threadIdx.x;
    int g = blockIdx.x * SCB + t;
    red[t] = (g < N_NODES) ? bend[g] : 0;
    __syncthreads();
    for (int s = SCB / 2; s > 0; s >>= 1) {
        if (t < s) red[t] += red[t + s];
        __syncthreads();
    }
    if (t == 0) partial[blockIdx.x] = red[0];
}

__global__ void scan2_kernel(int* __restrict__ partial) {
    int t = threadIdx.x;  // 64 threads, 1 wave
    int v = (t < SCAN_NBLK) ? partial[t] : 0;
    int incl = v;
    for (int off = 1; off < 64; off <<= 1) {
        int u = __shfl(incl, (t >= off) ? t - off : 0);
        if (t >= off) incl += u;
    }
    if (t < SCAN_NBLK) partial[t] = incl - v;  // exclusive
}

__global__ __launch_bounds__(SCB) void scan3_kernel(int* __restrict__ bend,
                                                    const int* __restrict__ partial) {
    __shared__ int sc[SCB];
    int t = threadIdx.x;
    int g = blockIdx.x * SCB + t;
    int v = (g < N_NODES) ? bend[g] : 0;
    sc[t] = v;
    __syncthreads();
    for (int off = 1; off < SCB; off <<= 1) {
        int u = (t >= off) ? sc[t - off] : 0;
        __syncthreads();
        sc[t] += u;
        __syncthreads();
    }
    if (g < N_NODES) bend[g] = sc[t] - v + partial[blockIdx.x];  // exclusive + block offset
}

__global__ void scatter_kernel(const int* __restrict__ dst, int* __restrict__ bend,
                               int* __restrict__ order) {
    int e = blockIdx.x * blockDim.x + threadIdx.x;
    if (e < N_EDGES) {
        int pos = atomicAdd(&bend[dst[e]], 1);
        order[pos] = e;
    }
}

// --- edge kernel (dst-sorted, N-split): one BLOCK per 32-edge tile; the block's
// two waves share one 16 KB f32 efeats tile and each computes 64 of the 128
// output columns (wave w: cols [64w, 64w+64), i.e. t_global = 4w + t, t in [0,4)).
// v = relu(concat(nfeats[src], efeats[e], nfeats[dst]) @ We + be)
// out1[e] = v + efeats[e];  sums[dst] += segmented in-register reduce of v.
__global__ __launch_bounds__(128, 4) void edge_kernel(
    const float* __restrict__ nfeats, const float* __restrict__ efeats,
    const int* __restrict__ src, const int* __restrict__ dst,
    const int* __restrict__ order,
    const unsigned short* __restrict__ We_shuf, const float* __restrict__ be,
    float* __restrict__ out1, float* __restrict__ sums) {
    __shared__ float ef_lds[32 * 128];  // 16 KB per block, shared by both waves
    int w = threadIdx.x >> 6;           // which column half
    int wid = blockIdx.x;
    int lane = threadIdx.x & 63;
    int e0 = wid * 32;
    int m = lane & 15, quad = lane >> 4;
    float* ef = &ef_lds[0];

    // lane i<32 owns sorted position e0+i
    int i = lane;
    int e_i = 0, d_i = 0;
    if (i < 32) {
        e_i = order[e0 + i];
        d_i = dst[e_i];
    }

    // stage 32 efeats rows into LDS, split across the 2 waves (wave0: rows 0-15,
    // wave1: rows 16-31); per-lane scattered source, swizzled chunk order.
#pragma unroll
    for (int it2 = 0; it2 < 8; ++it2) {
        int it = w * 8 + it2;
        int row = 2 * it + (lane >> 5);
        int er = __shfl(e_i, row);
        int c16 = (lane & 31) ^ (row & 7);
        gload16(efeats + (size_t)er * HID + c16 * 4, ef + it * 256);
    }

    // A-operand edges for rows m and 16+m (same for both waves)
    int ea = __shfl(e_i, m), eb = __shfl(e_i, 16 + m);
    int da = __shfl(d_i, m), db = __shfl(d_i, 16 + m);
    const float* s0 = nfeats + (size_t)src[ea] * HID;
    const float* s1 = nfeats + (size_t)src[eb] * HID;
    const float* d0 = nfeats + (size_t)da * HID;
    const float* d1 = nfeats + (size_t)db * HID;

    f32x4 acc[2][4];
#pragma unroll
    for (int mi = 0; mi < 2; ++mi)
#pragma unroll
        for (int t = 0; t < 4; ++t) acc[mi][t] = (f32x4){0.f, 0.f, 0.f, 0.f};

    const bf16x8* W = (const bf16x8*)We_shuf;
    int tbase = w * 4;  // this wave's first t

    // seg0: k in [0,128) from nfeats[src]
#pragma unroll
    for (int kk = 0; kk < 4; ++kk) {
        int off = kk * 32 + quad * 8;
        bf16x8 a0 = load_row8_bf16(s0 + off);
        bf16x8 a1 = load_row8_bf16(s1 + off);
#pragma unroll
        for (int t = 0; t < 4; ++t) {
            bf16x8 b = W[(kk * 8 + tbase + t) * 64 + lane];
            acc[0][t] = __builtin_amdgcn_mfma_f32_16x16x32_bf16(a0, b, acc[0][t], 0, 0, 0);
            acc[1][t] = __builtin_amdgcn_mfma_f32_16x16x32_bf16(a1, b, acc[1][t], 0, 0, 0);
        }
    }
    // seg2: k in [256,384) from nfeats[dst] (mostly broadcast: sorted by dst)
#pragma unroll
    for (int kk = 8; kk < 12; ++kk) {
        int off = (kk - 8) * 32 + quad * 8;
        bf16x8 a0 = load_row8_bf16(d0 + off);
        bf16x8 a1 = load_row8_bf16(d1 + off);
#pragma unroll
        for (int t = 0; t < 4; ++t) {
            bf16x8 b = W[(kk * 8 + tbase + t) * 64 + lane];
            acc[0][t] = __builtin_amdgcn_mfma_f32_16x16x32_bf16(a0, b, acc[0][t], 0, 0, 0);
            acc[1][t] = __builtin_amdgcn_mfma_f32_16x16x32_bf16(a1, b, acc[1][t], 0, 0, 0);
        }
    }

    // this wave's gload_lds complete, then cross-wave barrier (other half of tile)
    asm volatile("s_waitcnt vmcnt(0)" ::: "memory");
    __syncthreads();

    // seg1: k in [128,256) from LDS efeats
#pragma unroll
    for (int kk = 4; kk < 8; ++kk) {
        int c16 = (kk - 4) * 8 + quad * 2;
        bf16x8 a0 = load_frag_lds(ef, m, c16);
        bf16x8 a1 = load_frag_lds(ef, 16 + m, c16);
#pragma unroll
        for (int t = 0; t < 4; ++t) {
            bf16x8 b = W[(kk * 8 + tbase + t) * 64 + lane];
            acc[0][t] = __builtin_amdgcn_mfma_f32_16x16x32_bf16(a0, b, acc[0][t], 0, 0, 0);
            acc[1][t] = __builtin_amdgcn_mfma_f32_16x16x32_bf16(a1, b, acc[1][t], 0, 0, 0);
        }
    }

    float bev[4];
#pragma unroll
    for (int t = 0; t < 4; ++t) bev[t] = be[(tbase + t) * 16 + m];

    // epilogue: relu into acc (kept for reduction), out1[e] cols [64w,64w+64)
    // C/D layout: col = (tbase+t)*16 + m, window row = mi*16 + quad*4 + r
#pragma unroll
    for (int mi = 0; mi < 2; ++mi) {
#pragma unroll
        for (int r = 0; r < 4; ++r) {
            int lrow = mi * 16 + quad * 4 + r;
            int e = __shfl(e_i, lrow);
            float* o = out1 + (size_t)e * HID;
#pragma unroll
            for (int t = 0; t < 4; ++t) {
                int n = (tbase + t) * 16 + m;
                float v = fmaxf(acc[mi][t][r] + bev[t], 0.0f);
                acc[mi][t][r] = v;
                o[n] = v + lds_ef_read(ef, lrow, n);
            }
        }
    }

    // segmented reduction over sorted dst runs (this wave covers its 64 cols)
    int dprev = __shfl(d_i, (i == 0) ? 0 : i - 1);
    bool head = (i < 32) && (i == 0 || d_i != dprev);
    unsigned long long mask = __ballot(head);
    while (mask) {
        int a = __builtin_ctzll(mask);
        mask &= mask - 1;
        int b = mask ? __builtin_ctzll(mask) : 32;
        int nd = __shfl(d_i, a);
        float tot[4];
#pragma unroll
        for (int t = 0; t < 4; ++t) tot[t] = 0.f;
#pragma unroll
        for (int mi = 0; mi < 2; ++mi) {
#pragma unroll
            for (int r = 0; r < 4; ++r) {
                int lrow = mi * 16 + quad * 4 + r;
                bool in = (lrow >= a) && (lrow < b);
#pragma unroll
                for (int t = 0; t < 4; ++t) tot[t] += in ? acc[mi][t][r] : 0.0f;
            }
        }
#pragma unroll
        for (int t = 0; t < 4; ++t) {
            tot[t] += __shfl_xor(tot[t], 16);
            tot[t] += __shfl_xor(tot[t], 32);
        }
        // lane (m,quad) owns col (tbase+quad)*16 + m
        atomicAdd(&sums[(size_t)nd * HID + (tbase + quad) * 16 + m], tot[quad]);
    }
}

// --- node kernel: per wave, 16 nodes x 128 cols.
// h = sums/max(deg,1) with deg from bend diffs; out0 = relu(concat(nfeats,h)@Wn+bn)+nfeats
__global__ __launch_bounds__(256) void node_kernel(
    const float* __restrict__ nfeats, const unsigned short* __restrict__ Wn_shuf,
    const float* __restrict__ bn, const float* __restrict__ sums,
    const int* __restrict__ bend, float* __restrict__ out0) {
    int wid = blockIdx.x * 4 + (threadIdx.x >> 6);
    int n0 = wid * 16;
    if (n0 >= N_NODES) return;
    int lane = threadIdx.x & 63;
    int m = lane & 15, quad = lane >> 4;
    int row = n0 + m;
    int end = bend[row];
    int start = (row == 0) ? 0 : bend[row - 1];
    float inv = 1.0f / fmaxf((float)(end - start), 1.0f);
    const float* pn = nfeats + (size_t)row * HID;
    const float* ps = sums + (size_t)row * HID;

    f32x4 acc[8];
#pragma unroll
    for (int t = 0; t < 8; ++t) acc[t] = (f32x4){0.f, 0.f, 0.f, 0.f};

    const bf16x8* W = (const bf16x8*)Wn_shuf;

#pragma unroll
    for (int kk = 0; kk < 8; ++kk) {
        int k = kk * 32 + quad * 8;
        bf16x8 a = (k < 128) ? load_row8_bf16(pn + k)
                             : load_row8_bf16_scaled(ps + (k - 128), inv);
#pragma unroll
        for (int t = 0; t < 8; ++t) {
            bf16x8 b = W[(kk * 8 + t) * 64 + lane];
            acc[t] = __builtin_amdgcn_mfma_f32_16x16x32_bf16(a, b, acc[t], 0, 0, 0);
        }
    }

    float bnv[8];
#pragma unroll
    for (int t = 0; t < 8; ++t) bnv[t] = bn[t * 16 + m];

#pragma unroll
    for (int r = 0; r < 4; ++r) {
        int rw = n0 + quad * 4 + r;
        const float* nf = nfeats + (size_t)rw * HID;
        float* o = out0 + (size_t)rw * HID;
#pragma unroll
        for (int t = 0; t < 8; ++t) {
            int n = t * 16 + m;
            float v = fmaxf(acc[t][r] + bnv[t], 0.0f);
            o[n] = v + nf[n];
        }
    }
}

extern "C" void kernel_launch(void* const* d_in, const int* in_sizes, int n_in,
                              void* d_out, int out_size, void* d_ws, size_t ws_size,
                              hipStream_t stream) {
    const float* nfeats = (const float*)d_in[0];
    const float* efeats = (const float*)d_in[1];
    const int* src = (const int*)d_in[2];
    const int* dst = (const int*)d_in[3];
    const float* We = (const float*)d_in[4];
    const float* be = (const float*)d_in[5];
    const float* Wn = (const float*)d_in[6];
    const float* bn = (const float*)d_in[7];

    float* out0 = (float*)d_out;                       // [N_NODES, HID]
    float* out1 = out0 + (size_t)N_NODES * HID;        // [N_EDGES, HID]

    // order[] lives in the out0 region (dead until node_kernel, which runs last
    // and only starts after edge_kernel has fully consumed order): 3.2 MB.
    int* order = (int*)d_out;

    // workspace: sums (N*H fp32) | We_shuf | Wn_shuf | bend[N] | partial[64]
    float* sums = (float*)d_ws;
    unsigned short* We_shuf = (unsigned short*)(sums + (size_t)N_NODES * HID);
    unsigned short* Wn_shuf = We_shuf + WE_SHUF_ELEMS;
    int* bend = (int*)(Wn_shuf + WN_SHUF_ELEMS);  // byte off 25,763,840
    int* partial = bend + N_NODES;

    // zero sums (+shuf region, harmless: prep overwrites) + bend in one memset
    hipMemsetAsync(d_ws, 0,
                   (size_t)N_NODES * HID * 4 + (WE_SHUF_ELEMS + WN_SHUF_ELEMS) * 2 +
                       N_NODES * sizeof(int),
                   stream);

    prep_kernel<<<(WE_SHUF_ELEMS + WN_SHUF_ELEMS) / 256, 256, 0, stream>>>(We, Wn, We_shuf, Wn_shuf);

    hist_kernel<<<N_EDGES / 256, 256, 0, stream>>>(dst, bend);
    scan1_kernel<<<SCAN_NBLK, SCB, 0, stream>>>(bend, partial);
    scan2_kernel<<<1, 64, 0, stream>>>(partial);
    scan3_kernel<<<SCAN_NBLK, SCB, 0, stream>>>(bend, partial);
    scatter_kernel<<<N_EDGES / 256, 256, 0, stream>>>(dst, bend, order);

    // 800000 positions / 32 per block-tile = 25000 blocks (2 waves each, N-split)
    edge_kernel<<<25000, 128, 0, stream>>>(nfeats, efeats, src, dst, order,
                                           We_shuf, be, out1, sums);

    // 50000 nodes / 16 per wave = 3125 waves -> 782 blocks (guarded)
    node_kernel<<<782, 256, 0, stream>>>(nfeats, Wn_shuf, bn, sums, bend, out0);
}